// Round 1
// baseline (6543.378 us; speedup 1.0000x reference)
//
#include <hip/hip_runtime.h>

#define NV   50000
#define DCH  512
#define NEDGE 150000
#define MPAD 50048   // 391 * 128

typedef float  f32x4  __attribute__((ext_vector_type(4)));
typedef __bf16 bf16x8 __attribute__((ext_vector_type(8)));
typedef unsigned short us8 __attribute__((ext_vector_type(8)));

__device__ __forceinline__ unsigned short f2bf(float f) {
  unsigned int u = __builtin_bit_cast(unsigned int, f);
  u += 0x7fffu + ((u >> 16) & 1u);
  return (unsigned short)(u >> 16);
}

__device__ __forceinline__ void g2lds16(const void* g, void* l) {
  typedef const __attribute__((address_space(1))) unsigned int* gp_t;
  typedef __attribute__((address_space(3))) unsigned int* lp_t;
  __builtin_amdgcn_global_load_lds((gp_t)g, (lp_t)l, 16, 0, 0);
}

// wt[n*ldk + koff + k] = bf16(w[k*512 + n])   (w is [512][512] row-major)
__global__ void wt_kernel(const float* __restrict__ w, unsigned short* __restrict__ wt,
                          int ldk, int koff) {
  int idx = blockIdx.x * 256 + threadIdx.x;
  if (idx >= 512 * 512) return;
  int k = idx >> 9, n = idx & 511;
  wt[(size_t)n * ldk + koff + k] = f2bf(w[(size_t)k * 512 + n]);
}

__global__ void init_h(const float4* __restrict__ xa, const float4* __restrict__ xb,
                       float4* __restrict__ haa, float4* __restrict__ hba,
                       float4* __restrict__ hab) {
  int i = blockIdx.x * 256 + threadIdx.x;
  if (i >= NV * DCH / 4) return;
  float4 va = xa[i];
  haa[i] = va;
  hba[i] = va;
  hab[i] = xb[i];
}

// one wave per edge, 8 floats per lane
__global__ void scatter_add(const float* __restrict__ xsrc, const int* __restrict__ ei,
                            float* __restrict__ h) {
  int g = blockIdx.x * 256 + threadIdx.x;
  int e = g >> 6, lane = g & 63;
  if (e >= NEDGE) return;
  int s = ei[e], d = ei[NEDGE + e];
  const float* sp = xsrc + (size_t)s * DCH + lane * 8;
  float4 v0 = *(const float4*)sp;
  float4 v1 = *(const float4*)(sp + 4);
  float* dp = h + (size_t)d * DCH + lane * 8;
  unsafeAtomicAdd(dp + 0, v0.x); unsafeAtomicAdd(dp + 1, v0.y);
  unsafeAtomicAdd(dp + 2, v0.z); unsafeAtomicAdd(dp + 3, v0.w);
  unsafeAtomicAdd(dp + 4, v1.x); unsafeAtomicAdd(dp + 5, v1.y);
  unsafeAtomicAdd(dp + 6, v1.z); unsafeAtomicAdd(dp + 7, v1.w);
}

// fp32 [MPAD][512] -> bf16 [MPAD][512]; pad rows (>=NV) -> 0
__global__ void cvt_h(const float* __restrict__ src, unsigned short* __restrict__ dst) {
  int i = blockIdx.x * 256 + threadIdx.x;     // 8-elem chunk id
  if (i >= MPAD * 64) return;
  int row = i >> 6;
  float4 a = {0.f, 0.f, 0.f, 0.f}, b = {0.f, 0.f, 0.f, 0.f};
  if (row < NV) {
    const float* sp = src + (size_t)i * 8;
    a = *(const float4*)sp;
    b = *(const float4*)(sp + 4);
  }
  us8 o;
  o[0] = f2bf(a.x); o[1] = f2bf(a.y); o[2] = f2bf(a.z); o[3] = f2bf(a.w);
  o[4] = f2bf(b.x); o[5] = f2bf(b.y); o[6] = f2bf(b.z); o[7] = f2bf(b.w);
  *(us8*)(dst + (size_t)i * 8) = o;
}

// 128x128 tile, BK=64, 4 waves (2x2), 16x16x32 bf16 MFMA.
// A [*, lda] bf16 row-major (MPAD rows padded); Bt [512][ldb=K] bf16 (B transposed).
// MODE 0: out bf16, relu(acc + bias_a[col]), ldc/col_off apply.
// MODE 1: out fp32 = acc + bias_a[col] (+ bias_b[col]), row<NV guard.
template<int MODE>
__global__ void gemm_tile(const unsigned short* __restrict__ A, int lda,
                          const unsigned short* __restrict__ Bt, int ldb,
                          const float* __restrict__ bias_a,
                          const float* __restrict__ bias_b,
                          void* __restrict__ outp, int ldc, int col_off) {
  __shared__ __align__(16) unsigned short As[128 * 64];
  __shared__ __align__(16) unsigned short Bs[128 * 64];
  const int t = threadIdx.x;
  const int wave = t >> 6, lane = t & 63;
  const int wr = wave >> 1, wc = wave & 1;
  const int row_base = blockIdx.y * 128;
  const int col_base = blockIdx.x * 128;
  const int rl = lane & 15, kq = lane >> 4;

  f32x4 acc[4][4] = {};

  const int K = ldb;
  const int ktiles = K >> 6;
  for (int kt = 0; kt < ktiles; ++kt) {
    const int k0 = kt << 6;
#pragma unroll
    for (int i = 0; i < 4; ++i) {
      int q = i * 256 + t;
      int r = q >> 3, c = q & 7;
      int cg = c ^ (r & 7);   // pre-swizzled global source -> linear LDS dest
      g2lds16(A + (size_t)(row_base + r) * lda + k0 + cg * 8,
              &As[(size_t)(i * 256 + wave * 64) * 8]);
      g2lds16(Bt + (size_t)(col_base + r) * ldb + k0 + cg * 8,
              &Bs[(size_t)(i * 256 + wave * 64) * 8]);
    }
    __syncthreads();
#pragma unroll
    for (int kk = 0; kk < 2; ++kk) {
      bf16x8 af[4], bfr[4];
#pragma unroll
      for (int m = 0; m < 4; ++m) {
        int row = wr * 64 + m * 16 + rl;
        int cc = (kk * 4 + kq) ^ (row & 7);
        af[m] = *(const bf16x8*)&As[(row * 8 + cc) * 8];
      }
#pragma unroll
      for (int n = 0; n < 4; ++n) {
        int col = wc * 64 + n * 16 + rl;
        int cc = (kk * 4 + kq) ^ (col & 7);
        bfr[n] = *(const bf16x8*)&Bs[(col * 8 + cc) * 8];
      }
#pragma unroll
      for (int m = 0; m < 4; ++m)
#pragma unroll
        for (int n = 0; n < 4; ++n)
          acc[m][n] = __builtin_amdgcn_mfma_f32_16x16x32_bf16(af[m], bfr[n], acc[m][n], 0, 0, 0);
    }
    __syncthreads();
  }

  const int orow0 = row_base + wr * 64 + kq * 4;
  const int ocol0 = col_base + wc * 64 + rl;
  if (MODE == 0) {
    unsigned short* out = (unsigned short*)outp;
#pragma unroll
    for (int m = 0; m < 4; ++m)
#pragma unroll
      for (int n = 0; n < 4; ++n) {
        int col = ocol0 + n * 16;
        float bb = bias_a[col];
#pragma unroll
        for (int j = 0; j < 4; ++j) {
          int row = orow0 + m * 16 + j;
          float v = acc[m][n][j] + bb;
          v = fmaxf(v, 0.0f);
          out[(size_t)row * ldc + col_off + col] = f2bf(v);
        }
      }
  } else {
    float* out = (float*)outp;
#pragma unroll
    for (int m = 0; m < 4; ++m)
#pragma unroll
      for (int n = 0; n < 4; ++n) {
        int col = ocol0 + n * 16;
        float bb = bias_a[col] + (bias_b ? bias_b[col] : 0.0f);
#pragma unroll
        for (int j = 0; j < 4; ++j) {
          int row = orow0 + m * 16 + j;
          if (row < NV)
            out[(size_t)row * ldc + col] = acc[m][n][j] + bb;
        }
      }
  }
}

extern "C" void kernel_launch(void* const* d_in, const int* in_sizes, int n_in,
                              void* d_out, int out_size, void* d_ws, size_t ws_size,
                              hipStream_t stream) {
  const float* x_a  = (const float*)d_in[0];
  const float* x_b  = (const float*)d_in[1];
  const int* ei_aa  = (const int*)d_in[2];
  const int* ei_ab  = (const int*)d_in[3];
  const int* ei_ba  = (const int*)d_in[4];
  const float* w1_aa = (const float*)d_in[5];
  const float* b1_aa = (const float*)d_in[6];
  const float* w2_aa = (const float*)d_in[7];
  const float* b2_aa = (const float*)d_in[8];
  const float* w1_ab = (const float*)d_in[9];
  const float* b1_ab = (const float*)d_in[10];
  const float* w2_ab = (const float*)d_in[11];
  const float* b2_ab = (const float*)d_in[12];
  const float* w1_ba = (const float*)d_in[13];
  const float* b1_ba = (const float*)d_in[14];
  const float* w2_ba = (const float*)d_in[15];
  const float* b2_ba = (const float*)d_in[16];

  char* ws = (char*)d_ws;
  const size_t szF = (size_t)MPAD * DCH * 4;   // fp32 h buffer
  const size_t szH = (size_t)MPAD * DCH * 2;   // bf16 h buffer
  float* h_aa = (float*)(ws);
  float* h_ba = (float*)(ws + szF);
  float* h_ab = (float*)(ws + 2 * szF);
  unsigned short* hb_aa = (unsigned short*)(ws + 3 * szF);
  unsigned short* hb_ba = (unsigned short*)(ws + 3 * szF + szH);
  unsigned short* hb_ab = (unsigned short*)(ws + 3 * szF + 2 * szH);
  unsigned short* w1t_aa = (unsigned short*)(ws + 3 * szF + 3 * szH);
  unsigned short* w1t_ba = w1t_aa + 512 * 512;
  unsigned short* w1t_ab = w1t_ba + 512 * 512;
  unsigned short* w2tc   = w1t_ab + 512 * 512;   // [512][1024] stacked w2_aa|w2_ba
  unsigned short* w2t_ab = w2tc + 512 * 1024;
  // aliases (safe: fp32 h buffers dead once bf16 copies exist)
  unsigned short* H1c  = (unsigned short*)h_aa;   // [MPAD][1024] bf16
  unsigned short* H1ab = (unsigned short*)h_ba;   // [MPAD][512]  bf16

  float* out_a = (float*)d_out;
  float* out_b = out_a + (size_t)NV * DCH;

  wt_kernel<<<1024, 256, 0, stream>>>(w1_aa, w1t_aa, 512, 0);
  wt_kernel<<<1024, 256, 0, stream>>>(w1_ba, w1t_ba, 512, 0);
  wt_kernel<<<1024, 256, 0, stream>>>(w1_ab, w1t_ab, 512, 0);
  wt_kernel<<<1024, 256, 0, stream>>>(w2_aa, w2tc, 1024, 0);
  wt_kernel<<<1024, 256, 0, stream>>>(w2_ba, w2tc, 1024, 512);
  wt_kernel<<<1024, 256, 0, stream>>>(w2_ab, w2t_ab, 512, 0);

  init_h<<<25000, 256, 0, stream>>>((const float4*)x_a, (const float4*)x_b,
                                    (float4*)h_aa, (float4*)h_ba, (float4*)h_ab);

  scatter_add<<<37500, 256, 0, stream>>>(x_a, ei_aa, h_aa);
  scatter_add<<<37500, 256, 0, stream>>>(x_a, ei_ab, h_ab);
  scatter_add<<<37500, 256, 0, stream>>>(x_b, ei_ba, h_ba);

  cvt_h<<<12512, 256, 0, stream>>>(h_aa, hb_aa);
  cvt_h<<<12512, 256, 0, stream>>>(h_ba, hb_ba);
  cvt_h<<<12512, 256, 0, stream>>>(h_ab, hb_ab);

  dim3 g1(4, MPAD / 128);
  gemm_tile<0><<<g1, 256, 0, stream>>>(hb_aa, 512, w1t_aa, 512, b1_aa, nullptr, H1c, 1024, 0);
  gemm_tile<0><<<g1, 256, 0, stream>>>(hb_ba, 512, w1t_ba, 512, b1_ba, nullptr, H1c, 1024, 512);
  gemm_tile<0><<<g1, 256, 0, stream>>>(hb_ab, 512, w1t_ab, 512, b1_ab, nullptr, H1ab, 512, 0);

  gemm_tile<1><<<g1, 256, 0, stream>>>(H1c, 1024, w2tc, 1024, b2_aa, b2_ba, out_a, 512, 0);
  gemm_tile<1><<<g1, 256, 0, stream>>>(H1ab, 512, w2t_ab, 512, b2_ab, nullptr, out_b, 512, 0);
}

// Round 2
// 609.904 us; speedup vs baseline: 10.7285x; 10.7285x over previous
//
#include <hip/hip_runtime.h>

#define NV    50000
#define DCH   512
#define NEDGE 150000
#define MPAD  50048   // 391 * 128

typedef float  f32x4  __attribute__((ext_vector_type(4)));
typedef __bf16 bf16x8 __attribute__((ext_vector_type(8)));
typedef unsigned short us8 __attribute__((ext_vector_type(8)));

__device__ __forceinline__ unsigned short f2bf(float f) {
  unsigned int u = __builtin_bit_cast(unsigned int, f);
  u += 0x7fffu + ((u >> 16) & 1u);
  return (unsigned short)(u >> 16);
}

__device__ __forceinline__ void g2lds16(const void* g, void* l) {
  typedef const __attribute__((address_space(1))) unsigned int* gp_t;
  typedef __attribute__((address_space(3))) unsigned int* lp_t;
  __builtin_amdgcn_global_load_lds((gp_t)g, (lp_t)l, 16, 0, 0);
}

// wt[n*ldk + koff + k] = bf16(w[k*512 + n])   (w is [512][512] row-major)
__global__ void wt_kernel(const float* __restrict__ w, unsigned short* __restrict__ wt,
                          int ldk, int koff) {
  int idx = blockIdx.x * 256 + threadIdx.x;
  if (idx >= 512 * 512) return;
  int k = idx >> 9, n = idx & 511;
  wt[(size_t)n * ldk + koff + k] = f2bf(w[(size_t)k * 512 + n]);
}

// ---------------- CSR build ----------------
__global__ void hist_k(const int* __restrict__ ei, int* __restrict__ counts) {
  int e = blockIdx.x * 256 + threadIdx.x;
  if (e >= NEDGE) return;
  atomicAdd(&counts[ei[NEDGE + e]], 1);
}

__global__ void scan1(const int* __restrict__ counts, int* __restrict__ incl,
                      int* __restrict__ bsum) {
  __shared__ int sm[1024];
  int t = threadIdx.x, b = blockIdx.x;
  int i = b * 1024 + t;
  int v = (i < NV) ? counts[i] : 0;
  sm[t] = v; __syncthreads();
  for (int off = 1; off < 1024; off <<= 1) {
    int x = sm[t];
    int y = (t >= off) ? sm[t - off] : 0;
    __syncthreads();
    sm[t] = x + y;
    __syncthreads();
  }
  if (i < NV) incl[i] = sm[t];
  if (t == 1023) bsum[b] = sm[t];
}

__global__ void scan2(const int* __restrict__ bsum, int* __restrict__ boff, int nb) {
  if (threadIdx.x == 0 && blockIdx.x == 0) {
    int run = 0;
    for (int b = 0; b < nb; ++b) { boff[b] = run; run += bsum[b]; }
  }
}

__global__ void scan3(const int* __restrict__ incl, const int* __restrict__ counts,
                      const int* __restrict__ boff, int* __restrict__ off) {
  int i = blockIdx.x * 256 + threadIdx.x;
  if (i < NV) off[i] = incl[i] - counts[i] + boff[i >> 10];
  if (i == NV) off[NV] = NEDGE;
}

__global__ void fill_csr(const int* __restrict__ ei, const int* __restrict__ off,
                         int* __restrict__ cursor, int* __restrict__ csrc) {
  int e = blockIdx.x * 256 + threadIdx.x;
  if (e >= NEDGE) return;
  int d = ei[NEDGE + e];
  int pos = off[d] + atomicAdd(&cursor[d], 1);
  csrc[pos] = ei[e];
}

// ---------------- gather: hb[node] = bf16(x_dst[node] + sum_{e in CSR} x_src[src_e]) ----
// one wave per node (8 floats/lane); pad rows -> 0
__global__ void gather_h(const float* __restrict__ xdst, const float* __restrict__ xsrc,
                         const int* __restrict__ off, const int* __restrict__ csrc,
                         unsigned short* __restrict__ hb) {
  int g = blockIdx.x * 256 + threadIdx.x;
  int node = g >> 6, lane = g & 63;
  if (node >= MPAD) return;
  unsigned short* op = hb + (size_t)node * DCH + lane * 8;
  if (node >= NV) {
    us8 z = {0, 0, 0, 0, 0, 0, 0, 0};
    *(us8*)op = z;
    return;
  }
  const float* dp = xdst + (size_t)node * DCH + lane * 8;
  float4 a = *(const float4*)dp;
  float4 b = *(const float4*)(dp + 4);
  int s0 = off[node], s1 = off[node + 1];
  for (int i = s0; i < s1; ++i) {
    int s = csrc[i];   // uniform per wave
    const float* sp = xsrc + (size_t)s * DCH + lane * 8;
    float4 u = *(const float4*)sp;
    float4 v = *(const float4*)(sp + 4);
    a.x += u.x; a.y += u.y; a.z += u.z; a.w += u.w;
    b.x += v.x; b.y += v.y; b.z += v.z; b.w += v.w;
  }
  us8 o;
  o[0] = f2bf(a.x); o[1] = f2bf(a.y); o[2] = f2bf(a.z); o[3] = f2bf(a.w);
  o[4] = f2bf(b.x); o[5] = f2bf(b.y); o[6] = f2bf(b.z); o[7] = f2bf(b.w);
  *(us8*)op = o;
}

// ---------------- GEMM (unchanged from r1, validated) ----------------
// 128x128 tile, BK=64, 4 waves (2x2), 16x16x32 bf16 MFMA.
template<int MODE>
__global__ void gemm_tile(const unsigned short* __restrict__ A, int lda,
                          const unsigned short* __restrict__ Bt, int ldb,
                          const float* __restrict__ bias_a,
                          const float* __restrict__ bias_b,
                          void* __restrict__ outp, int ldc, int col_off) {
  __shared__ __align__(16) unsigned short As[128 * 64];
  __shared__ __align__(16) unsigned short Bs[128 * 64];
  const int t = threadIdx.x;
  const int wave = t >> 6, lane = t & 63;
  const int wr = wave >> 1, wc = wave & 1;
  const int row_base = blockIdx.y * 128;
  const int col_base = blockIdx.x * 128;
  const int rl = lane & 15, kq = lane >> 4;

  f32x4 acc[4][4] = {};

  const int K = ldb;
  const int ktiles = K >> 6;
  for (int kt = 0; kt < ktiles; ++kt) {
    const int k0 = kt << 6;
#pragma unroll
    for (int i = 0; i < 4; ++i) {
      int q = i * 256 + t;
      int r = q >> 3, c = q & 7;
      int cg = c ^ (r & 7);   // pre-swizzled global source -> linear LDS dest
      g2lds16(A + (size_t)(row_base + r) * lda + k0 + cg * 8,
              &As[(size_t)(i * 256 + wave * 64) * 8]);
      g2lds16(Bt + (size_t)(col_base + r) * ldb + k0 + cg * 8,
              &Bs[(size_t)(i * 256 + wave * 64) * 8]);
    }
    __syncthreads();
#pragma unroll
    for (int kk = 0; kk < 2; ++kk) {
      bf16x8 af[4], bfr[4];
#pragma unroll
      for (int m = 0; m < 4; ++m) {
        int row = wr * 64 + m * 16 + rl;
        int cc = (kk * 4 + kq) ^ (row & 7);
        af[m] = *(const bf16x8*)&As[(row * 8 + cc) * 8];
      }
#pragma unroll
      for (int n = 0; n < 4; ++n) {
        int col = wc * 64 + n * 16 + rl;
        int cc = (kk * 4 + kq) ^ (col & 7);
        bfr[n] = *(const bf16x8*)&Bs[(col * 8 + cc) * 8];
      }
#pragma unroll
      for (int m = 0; m < 4; ++m)
#pragma unroll
        for (int n = 0; n < 4; ++n)
          acc[m][n] = __builtin_amdgcn_mfma_f32_16x16x32_bf16(af[m], bfr[n], acc[m][n], 0, 0, 0);
    }
    __syncthreads();
  }

  const int orow0 = row_base + wr * 64 + kq * 4;
  const int ocol0 = col_base + wc * 64 + rl;
  if (MODE == 0) {
    unsigned short* out = (unsigned short*)outp;
#pragma unroll
    for (int m = 0; m < 4; ++m)
#pragma unroll
      for (int n = 0; n < 4; ++n) {
        int col = ocol0 + n * 16;
        float bb = bias_a[col];
#pragma unroll
        for (int j = 0; j < 4; ++j) {
          int row = orow0 + m * 16 + j;
          float v = acc[m][n][j] + bb;
          v = fmaxf(v, 0.0f);
          out[(size_t)row * ldc + col_off + col] = f2bf(v);
        }
      }
  } else {
    float* out = (float*)outp;
#pragma unroll
    for (int m = 0; m < 4; ++m)
#pragma unroll
      for (int n = 0; n < 4; ++n) {
        int col = ocol0 + n * 16;
        float bb = bias_a[col] + (bias_b ? bias_b[col] : 0.0f);
#pragma unroll
        for (int j = 0; j < 4; ++j) {
          int row = orow0 + m * 16 + j;
          if (row < NV)
            out[(size_t)row * ldc + col] = acc[m][n][j] + bb;
        }
      }
  }
}

extern "C" void kernel_launch(void* const* d_in, const int* in_sizes, int n_in,
                              void* d_out, int out_size, void* d_ws, size_t ws_size,
                              hipStream_t stream) {
  const float* x_a  = (const float*)d_in[0];
  const float* x_b  = (const float*)d_in[1];
  const int* ei_aa  = (const int*)d_in[2];
  const int* ei_ab  = (const int*)d_in[3];
  const int* ei_ba  = (const int*)d_in[4];
  const float* w1_aa = (const float*)d_in[5];
  const float* b1_aa = (const float*)d_in[6];
  const float* w2_aa = (const float*)d_in[7];
  const float* b2_aa = (const float*)d_in[8];
  const float* w1_ab = (const float*)d_in[9];
  const float* b1_ab = (const float*)d_in[10];
  const float* w2_ab = (const float*)d_in[11];
  const float* b2_ab = (const float*)d_in[12];
  const float* w1_ba = (const float*)d_in[13];
  const float* b1_ba = (const float*)d_in[14];
  const float* w2_ba = (const float*)d_in[15];
  const float* b2_ba = (const float*)d_in[16];

  char* ws = (char*)d_ws;
  const size_t szH  = (size_t)MPAD * DCH * 2;          // bf16 [MPAD][512]
  const size_t szH2 = (size_t)MPAD * DCH * 2 * 2;      // bf16 [MPAD][1024]
  size_t o = 0;
  unsigned short* hb_aa = (unsigned short*)(ws + o); o += szH;
  unsigned short* hb_ba = (unsigned short*)(ws + o); o += szH;
  unsigned short* hb_ab = (unsigned short*)(ws + o); o += szH;
  unsigned short* H1c   = (unsigned short*)(ws + o); o += szH2;  // [MPAD][1024]
  unsigned short* H1ab  = (unsigned short*)(ws + o); o += szH;
  unsigned short* w1t_aa = (unsigned short*)(ws + o); o += 512 * 512 * 2;
  unsigned short* w1t_ba = (unsigned short*)(ws + o); o += 512 * 512 * 2;
  unsigned short* w1t_ab = (unsigned short*)(ws + o); o += 512 * 512 * 2;
  unsigned short* w2tc   = (unsigned short*)(ws + o); o += 512 * 1024 * 2;
  unsigned short* w2t_ab = (unsigned short*)(ws + o); o += 512 * 512 * 2;

  const int NB1 = (NV + 1023) / 1024;                  // 49
  struct Csr { int *counts, *cursor, *incl, *off, *csrc, *bsum, *boff; };
  Csr cs[3];
  for (int tI = 0; tI < 3; ++tI) {
    cs[tI].counts = (int*)(ws + o); o += (size_t)NV * 4;
    cs[tI].cursor = (int*)(ws + o); o += (size_t)NV * 4;
    cs[tI].incl   = (int*)(ws + o); o += (size_t)NV * 4;
    cs[tI].off    = (int*)(ws + o); o += ((size_t)NV + 4) * 4;
    cs[tI].csrc   = (int*)(ws + o); o += (size_t)NEDGE * 4;
    cs[tI].bsum   = (int*)(ws + o); o += 64 * 4;
    cs[tI].boff   = (int*)(ws + o); o += 64 * 4;
  }

  float* out_a = (float*)d_out;
  float* out_b = out_a + (size_t)NV * DCH;

  // weights -> bf16 transposed (tiny)
  wt_kernel<<<1024, 256, 0, stream>>>(w1_aa, w1t_aa, 512, 0);
  wt_kernel<<<1024, 256, 0, stream>>>(w1_ba, w1t_ba, 512, 0);
  wt_kernel<<<1024, 256, 0, stream>>>(w1_ab, w1t_ab, 512, 0);
  wt_kernel<<<1024, 256, 0, stream>>>(w2_aa, w2tc, 1024, 0);
  wt_kernel<<<1024, 256, 0, stream>>>(w2_ba, w2tc, 1024, 512);
  wt_kernel<<<1024, 256, 0, stream>>>(w2_ab, w2t_ab, 512, 0);

  const int* eis[3] = { ei_aa, ei_ab, ei_ba };
  for (int tI = 0; tI < 3; ++tI) {
    hipMemsetAsync(cs[tI].counts, 0, (size_t)NV * 4, stream);
    hipMemsetAsync(cs[tI].cursor, 0, (size_t)NV * 4, stream);
    hist_k<<<(NEDGE + 255) / 256, 256, 0, stream>>>(eis[tI], cs[tI].counts);
    scan1<<<NB1, 1024, 0, stream>>>(cs[tI].counts, cs[tI].incl, cs[tI].bsum);
    scan2<<<1, 64, 0, stream>>>(cs[tI].bsum, cs[tI].boff, NB1);
    scan3<<<(NV + 256) / 256, 256, 0, stream>>>(cs[tI].incl, cs[tI].counts,
                                                cs[tI].boff, cs[tI].off);
    fill_csr<<<(NEDGE + 255) / 256, 256, 0, stream>>>(eis[tI], cs[tI].off,
                                                      cs[tI].cursor, cs[tI].csrc);
  }

  // gathers: h = x_dst + sum(x_src)   (aa: a<-a, ab: b<-a, ba: a<-b)
  const int GB = MPAD / 4;   // one wave per node
  gather_h<<<GB, 256, 0, stream>>>(x_a, x_a, cs[0].off, cs[0].csrc, hb_aa);
  gather_h<<<GB, 256, 0, stream>>>(x_b, x_a, cs[1].off, cs[1].csrc, hb_ab);
  gather_h<<<GB, 256, 0, stream>>>(x_a, x_b, cs[2].off, cs[2].csrc, hb_ba);

  dim3 g1(4, MPAD / 128);
  gemm_tile<0><<<g1, 256, 0, stream>>>(hb_aa, 512, w1t_aa, 512, b1_aa, nullptr, H1c, 1024, 0);
  gemm_tile<0><<<g1, 256, 0, stream>>>(hb_ba, 512, w1t_ba, 512, b1_ba, nullptr, H1c, 1024, 512);
  gemm_tile<0><<<g1, 256, 0, stream>>>(hb_ab, 512, w1t_ab, 512, b1_ab, nullptr, H1ab, 512, 0);

  gemm_tile<1><<<g1, 256, 0, stream>>>(H1c, 1024, w2tc, 1024, b2_aa, b2_ba, out_a, 512, 0);
  gemm_tile<1><<<g1, 256, 0, stream>>>(H1ab, 512, w2t_ab, 512, b2_ab, nullptr, out_b, 512, 0);
}

// Round 3
// 528.549 us; speedup vs baseline: 12.3799x; 1.1539x over previous
//
#include <hip/hip_runtime.h>

#define NV    50000
#define DCH   512
#define NEDGE 150000
#define MPAD  50048   // 391 * 128

typedef float  f32x4  __attribute__((ext_vector_type(4)));
typedef __bf16 bf16x8 __attribute__((ext_vector_type(8)));
typedef unsigned short us8 __attribute__((ext_vector_type(8)));

__device__ __forceinline__ unsigned short f2bf(float f) {
  unsigned int u = __builtin_bit_cast(unsigned int, f);
  u += 0x7fffu + ((u >> 16) & 1u);
  return (unsigned short)(u >> 16);
}

__device__ __forceinline__ void g2lds16(const void* g, void* l) {
  typedef const __attribute__((address_space(1))) unsigned int* gp_t;
  typedef __attribute__((address_space(3))) unsigned int* lp_t;
  __builtin_amdgcn_global_load_lds((gp_t)g, (lp_t)l, 16, 0, 0);
}

// ---------------- weight transpose+cvt, z-batched ----------------
struct WtJob  { const float* w; unsigned short* dst; int ldk, koff; };
struct WtJobs { WtJob j[6]; };

__global__ void wt_kernel(WtJobs jobs) {
  const WtJob J = jobs.j[blockIdx.z];
  int idx = blockIdx.x * 256 + threadIdx.x;
  if (idx >= 512 * 512) return;
  int k = idx >> 9, n = idx & 511;
  J.dst[(size_t)n * J.ldk + J.koff + k] = f2bf(J.w[(size_t)k * 512 + n]);
}

// ---------------- CSR build, z-batched over the 3 edge types ----------------
struct CsrP  { const int* ei; int* counts; int* cursor; int* incl; int* off; int* csrc; int* bsum; int* boff; };
struct Csr3  { CsrP c[3]; };

__global__ void hist_k(Csr3 cs) {
  const CsrP C = cs.c[blockIdx.z];
  int e = blockIdx.x * 256 + threadIdx.x;
  if (e >= NEDGE) return;
  atomicAdd(&C.counts[C.ei[NEDGE + e]], 1);
}

__global__ void scan1(Csr3 cs) {
  const CsrP C = cs.c[blockIdx.z];
  __shared__ int sm[1024];
  int t = threadIdx.x, b = blockIdx.x;
  int i = b * 1024 + t;
  int v = (i < NV) ? C.counts[i] : 0;
  sm[t] = v; __syncthreads();
  for (int off = 1; off < 1024; off <<= 1) {
    int x = sm[t];
    int y = (t >= off) ? sm[t - off] : 0;
    __syncthreads();
    sm[t] = x + y;
    __syncthreads();
  }
  if (i < NV) C.incl[i] = sm[t];
  if (t == 1023) C.bsum[b] = sm[t];
}

__global__ void scan2(Csr3 cs, int nb) {
  const CsrP C = cs.c[blockIdx.z];
  if (threadIdx.x == 0) {
    int run = 0;
    for (int b = 0; b < nb; ++b) { C.boff[b] = run; run += C.bsum[b]; }
  }
}

__global__ void scan3(Csr3 cs) {
  const CsrP C = cs.c[blockIdx.z];
  int i = blockIdx.x * 256 + threadIdx.x;
  if (i < NV) {
    int v = C.incl[i] - C.counts[i] + C.boff[i >> 10];
    C.off[i] = v;
    C.cursor[i] = v;           // live cursor starts at row offset
  }
  if (i == NV) C.off[NV] = NEDGE;
}

__global__ void fill_csr(Csr3 cs) {
  const CsrP C = cs.c[blockIdx.z];
  int e = blockIdx.x * 256 + threadIdx.x;
  if (e >= NEDGE) return;
  int d = C.ei[NEDGE + e];
  int pos = atomicAdd(&C.cursor[d], 1);
  C.csrc[pos] = C.ei[e];
}

// ---------------- merged gather: all 3 edge types in one pass ----------------
__device__ __forceinline__ void acc_rows(const float* __restrict__ xsrc,
                                         const int* __restrict__ csrc,
                                         int s0, int s1, int lane,
                                         float4& a, float4& b) {
  int i = s0;
  for (; i + 1 < s1; i += 2) {
    int sA = csrc[i], sB = csrc[i + 1];
    const float* pA = xsrc + (size_t)sA * DCH + lane * 8;
    const float* pB = xsrc + (size_t)sB * DCH + lane * 8;
    float4 uA = *(const float4*)pA, vA = *(const float4*)(pA + 4);
    float4 uB = *(const float4*)pB, vB = *(const float4*)(pB + 4);
    a.x += uA.x + uB.x; a.y += uA.y + uB.y; a.z += uA.z + uB.z; a.w += uA.w + uB.w;
    b.x += vA.x + vB.x; b.y += vA.y + vB.y; b.z += vA.z + vB.z; b.w += vA.w + vB.w;
  }
  if (i < s1) {
    int s = csrc[i];
    const float* p = xsrc + (size_t)s * DCH + lane * 8;
    float4 u = *(const float4*)p, v = *(const float4*)(p + 4);
    a.x += u.x; a.y += u.y; a.z += u.z; a.w += u.w;
    b.x += v.x; b.y += v.y; b.z += v.z; b.w += v.w;
  }
}

__device__ __forceinline__ void store_bf16x8(unsigned short* op, float4 a, float4 b) {
  us8 o;
  o[0] = f2bf(a.x); o[1] = f2bf(a.y); o[2] = f2bf(a.z); o[3] = f2bf(a.w);
  o[4] = f2bf(b.x); o[5] = f2bf(b.y); o[6] = f2bf(b.z); o[7] = f2bf(b.w);
  *(us8*)op = o;
}

__global__ void gather_all(const float* __restrict__ xa, const float* __restrict__ xb,
                           const int* __restrict__ off_aa, const int* __restrict__ src_aa,
                           const int* __restrict__ off_ba, const int* __restrict__ src_ba,
                           const int* __restrict__ off_ab, const int* __restrict__ src_ab,
                           unsigned short* __restrict__ hb_aa,
                           unsigned short* __restrict__ hb_ba,
                           unsigned short* __restrict__ hb_ab) {
  int g = blockIdx.x * 256 + threadIdx.x;
  int node = g >> 6, lane = g & 63;
  if (node >= MPAD) return;
  size_t obase = (size_t)node * DCH + lane * 8;
  if (node >= NV) {
    us8 z = {0, 0, 0, 0, 0, 0, 0, 0};
    *(us8*)(hb_aa + obase) = z;
    *(us8*)(hb_ba + obase) = z;
    *(us8*)(hb_ab + obase) = z;
    return;
  }
  const float* dpa = xa + obase;
  float4 a0 = *(const float4*)dpa;
  float4 a1 = *(const float4*)(dpa + 4);
  const float* dpb = xb + obase;
  float4 aa0 = a0, aa1 = a1;          // h_aa = x_a + sum(x_a srcs)
  float4 ba0 = a0, ba1 = a1;          // h_ba = x_a + sum(x_b srcs)
  float4 ab0 = *(const float4*)dpb;   // h_ab = x_b + sum(x_a srcs)
  float4 ab1 = *(const float4*)(dpb + 4);

  acc_rows(xa, src_aa, off_aa[node], off_aa[node + 1], lane, aa0, aa1);
  acc_rows(xb, src_ba, off_ba[node], off_ba[node + 1], lane, ba0, ba1);
  acc_rows(xa, src_ab, off_ab[node], off_ab[node + 1], lane, ab0, ab1);

  store_bf16x8(hb_aa + obase, aa0, aa1);
  store_bf16x8(hb_ba + obase, ba0, ba1);
  store_bf16x8(hb_ab + obase, ab0, ab1);
}

// ---------------- GEMM, z-batched ----------------
// 128x128 tile, BK=64, 4 waves (2x2), 16x16x32 bf16 MFMA.
// MODE 0: out bf16, relu(acc + bias_a[col]), ldc/col_off apply.
// MODE 1: out fp32 = acc + bias_a[col] (+ bias_b[col]), row<NV guard.
struct GemmJob  { const unsigned short* A; int lda; const unsigned short* Bt; int ldb;
                  const float* bias_a; const float* bias_b; void* out; int ldc; int col_off; };
struct GemmJobs { GemmJob j[3]; };

template<int MODE>
__global__ void gemm_tile(GemmJobs jobs) {
  const GemmJob J = jobs.j[blockIdx.z];
  __shared__ __align__(16) unsigned short As[128 * 64];
  __shared__ __align__(16) unsigned short Bs[128 * 64];
  const int t = threadIdx.x;
  const int wave = t >> 6, lane = t & 63;
  const int wr = wave >> 1, wc = wave & 1;
  const int row_base = blockIdx.y * 128;
  const int col_base = blockIdx.x * 128;
  const int rl = lane & 15, kq = lane >> 4;

  f32x4 acc[4][4] = {};

  const int K = J.ldb;
  const int ktiles = K >> 6;
  const unsigned short* Ap = J.A;
  const unsigned short* Bp = J.Bt;
  const int lda = J.lda, ldb = J.ldb;
  for (int kt = 0; kt < ktiles; ++kt) {
    const int k0 = kt << 6;
#pragma unroll
    for (int i = 0; i < 4; ++i) {
      int q = i * 256 + t;
      int r = q >> 3, c = q & 7;
      int cg = c ^ (r & 7);   // pre-swizzled global source -> linear LDS dest
      g2lds16(Ap + (size_t)(row_base + r) * lda + k0 + cg * 8,
              &As[(size_t)(i * 256 + wave * 64) * 8]);
      g2lds16(Bp + (size_t)(col_base + r) * ldb + k0 + cg * 8,
              &Bs[(size_t)(i * 256 + wave * 64) * 8]);
    }
    __syncthreads();
#pragma unroll
    for (int kk = 0; kk < 2; ++kk) {
      bf16x8 af[4], bfr[4];
#pragma unroll
      for (int m = 0; m < 4; ++m) {
        int row = wr * 64 + m * 16 + rl;
        int cc = (kk * 4 + kq) ^ (row & 7);
        af[m] = *(const bf16x8*)&As[(row * 8 + cc) * 8];
      }
#pragma unroll
      for (int n = 0; n < 4; ++n) {
        int col = wc * 64 + n * 16 + rl;
        int cc = (kk * 4 + kq) ^ (col & 7);
        bfr[n] = *(const bf16x8*)&Bs[(col * 8 + cc) * 8];
      }
#pragma unroll
      for (int m = 0; m < 4; ++m)
#pragma unroll
        for (int n = 0; n < 4; ++n)
          acc[m][n] = __builtin_amdgcn_mfma_f32_16x16x32_bf16(af[m], bfr[n], acc[m][n], 0, 0, 0);
    }
    __syncthreads();
  }

  const int orow0 = row_base + wr * 64 + kq * 4;
  const int ocol0 = col_base + wc * 64 + rl;
  if (MODE == 0) {
    unsigned short* out = (unsigned short*)J.out;
#pragma unroll
    for (int m = 0; m < 4; ++m)
#pragma unroll
      for (int n = 0; n < 4; ++n) {
        int col = ocol0 + n * 16;
        float bb = J.bias_a[col];
#pragma unroll
        for (int j = 0; j < 4; ++j) {
          int row = orow0 + m * 16 + j;
          float v = acc[m][n][j] + bb;
          v = fmaxf(v, 0.0f);
          out[(size_t)row * J.ldc + J.col_off + col] = f2bf(v);
        }
      }
  } else {
    float* out = (float*)J.out;
#pragma unroll
    for (int m = 0; m < 4; ++m)
#pragma unroll
      for (int n = 0; n < 4; ++n) {
        int col = ocol0 + n * 16;
        float bb = J.bias_a[col] + (J.bias_b ? J.bias_b[col] : 0.0f);
#pragma unroll
        for (int j = 0; j < 4; ++j) {
          int row = orow0 + m * 16 + j;
          if (row < NV)
            out[(size_t)row * J.ldc + col] = acc[m][n][j] + bb;
        }
      }
  }
}

extern "C" void kernel_launch(void* const* d_in, const int* in_sizes, int n_in,
                              void* d_out, int out_size, void* d_ws, size_t ws_size,
                              hipStream_t stream) {
  const float* x_a  = (const float*)d_in[0];
  const float* x_b  = (const float*)d_in[1];
  const int* ei_aa  = (const int*)d_in[2];
  const int* ei_ab  = (const int*)d_in[3];
  const int* ei_ba  = (const int*)d_in[4];
  const float* w1_aa = (const float*)d_in[5];
  const float* b1_aa = (const float*)d_in[6];
  const float* w2_aa = (const float*)d_in[7];
  const float* b2_aa = (const float*)d_in[8];
  const float* w1_ab = (const float*)d_in[9];
  const float* b1_ab = (const float*)d_in[10];
  const float* w2_ab = (const float*)d_in[11];
  const float* b2_ab = (const float*)d_in[12];
  const float* w1_ba = (const float*)d_in[13];
  const float* b1_ba = (const float*)d_in[14];
  const float* w2_ba = (const float*)d_in[15];
  const float* b2_ba = (const float*)d_in[16];

  char* ws = (char*)d_ws;
  const size_t szH  = (size_t)MPAD * DCH * 2;          // bf16 [MPAD][512]
  const size_t szH2 = (size_t)MPAD * DCH * 2 * 2;      // bf16 [MPAD][1024]
  size_t o = 0;
  unsigned short* hb_aa = (unsigned short*)(ws + o); o += szH;
  unsigned short* hb_ba = (unsigned short*)(ws + o); o += szH;
  unsigned short* hb_ab = (unsigned short*)(ws + o); o += szH;
  unsigned short* H1c   = (unsigned short*)(ws + o); o += szH2;  // [MPAD][1024]
  unsigned short* H1ab  = (unsigned short*)(ws + o); o += szH;
  unsigned short* w1t_aa = (unsigned short*)(ws + o); o += 512 * 512 * 2;
  unsigned short* w1t_ba = (unsigned short*)(ws + o); o += 512 * 512 * 2;
  unsigned short* w1t_ab = (unsigned short*)(ws + o); o += 512 * 512 * 2;
  unsigned short* w2tc   = (unsigned short*)(ws + o); o += 512 * 1024 * 2;
  unsigned short* w2t_ab = (unsigned short*)(ws + o); o += 512 * 512 * 2;

  // counts for the 3 types contiguous -> one memset
  int* counts3 = (int*)(ws + o); o += (size_t)3 * NV * 4;

  const int NB1 = (NV + 1023) / 1024;                  // 49
  Csr3 cs;
  const int* eis[3] = { ei_aa, ei_ab, ei_ba };
  for (int tI = 0; tI < 3; ++tI) {
    cs.c[tI].ei     = eis[tI];
    cs.c[tI].counts = counts3 + (size_t)tI * NV;
    cs.c[tI].cursor = (int*)(ws + o); o += (size_t)NV * 4;
    cs.c[tI].incl   = (int*)(ws + o); o += (size_t)NV * 4;
    cs.c[tI].off    = (int*)(ws + o); o += ((size_t)NV + 4) * 4;
    cs.c[tI].csrc   = (int*)(ws + o); o += (size_t)NEDGE * 4;
    cs.c[tI].bsum   = (int*)(ws + o); o += 64 * 4;
    cs.c[tI].boff   = (int*)(ws + o); o += 64 * 4;
  }

  float* out_a = (float*)d_out;
  float* out_b = out_a + (size_t)NV * DCH;

  // weights -> bf16 transposed, one launch
  WtJobs wj;
  wj.j[0] = { w1_aa, w1t_aa, 512, 0 };
  wj.j[1] = { w1_ba, w1t_ba, 512, 0 };
  wj.j[2] = { w1_ab, w1t_ab, 512, 0 };
  wj.j[3] = { w2_aa, w2tc, 1024, 0 };
  wj.j[4] = { w2_ba, w2tc, 1024, 512 };
  wj.j[5] = { w2_ab, w2t_ab, 512, 0 };
  wt_kernel<<<dim3(1024, 1, 6), 256, 0, stream>>>(wj);

  // CSR build (4 launches + 1 memset)
  hipMemsetAsync(counts3, 0, (size_t)3 * NV * 4, stream);
  hist_k<<<dim3(587, 1, 3), 256, 0, stream>>>(cs);
  scan1<<<dim3(NB1, 1, 3), 1024, 0, stream>>>(cs);
  scan2<<<dim3(1, 1, 3), 64, 0, stream>>>(cs, NB1);
  scan3<<<dim3(196, 1, 3), 256, 0, stream>>>(cs);
  fill_csr<<<dim3(587, 1, 3), 256, 0, stream>>>(cs);

  // merged gather (aa: a<-a, ba: a<-b, ab: b<-a)
  gather_all<<<MPAD / 4, 256, 0, stream>>>(
      x_a, x_b,
      cs.c[0].off, cs.c[0].csrc,      // aa
      cs.c[2].off, cs.c[2].csrc,      // ba
      cs.c[1].off, cs.c[1].csrc,      // ab
      hb_aa, hb_ba, hb_ab);

  // layer 1: 3 GEMMs in one launch
  GemmJobs g1;
  g1.j[0] = { hb_aa, 512, w1t_aa, 512, b1_aa, nullptr, H1c,  1024, 0 };
  g1.j[1] = { hb_ba, 512, w1t_ba, 512, b1_ba, nullptr, H1c,  1024, 512 };
  g1.j[2] = { hb_ab, 512, w1t_ab, 512, b1_ab, nullptr, H1ab, 512,  0 };
  gemm_tile<0><<<dim3(4, MPAD / 128, 3), 256, 0, stream>>>(g1);

  // layer 2: merged-K GEMM (aa+ba) and ab GEMM in one launch
  GemmJobs g2;
  g2.j[0] = { H1c,  1024, w2tc,   1024, b2_aa, b2_ba,  out_a, 512, 0 };
  g2.j[1] = { H1ab, 512,  w2t_ab, 512,  b2_ab, nullptr, out_b, 512, 0 };
  g2.j[2] = g2.j[1];   // unused (grid z=2)
  gemm_tile<1><<<dim3(4, MPAD / 128, 2), 256, 0, stream>>>(g2);
}

// Round 4
// 494.096 us; speedup vs baseline: 13.2431x; 1.0697x over previous
//
#include <hip/hip_runtime.h>

#define NV    50000
#define DCH   512
#define NEDGE 150000
#define MPAD  50048   // 391 * 128

typedef float  f32x4  __attribute__((ext_vector_type(4)));
typedef __bf16 bf16x8 __attribute__((ext_vector_type(8)));
typedef unsigned short us8 __attribute__((ext_vector_type(8)));

__device__ __forceinline__ unsigned short f2bf(float f) {
  unsigned int u = __builtin_bit_cast(unsigned int, f);
  u += 0x7fffu + ((u >> 16) & 1u);
  return (unsigned short)(u >> 16);
}

__device__ __forceinline__ float bf2f(unsigned short h) {
  return __builtin_bit_cast(float, (unsigned int)h << 16);
}

__device__ __forceinline__ void g2lds16(const void* g, void* l) {
  typedef const __attribute__((address_space(1))) unsigned int* gp_t;
  typedef __attribute__((address_space(3))) unsigned int* lp_t;
  __builtin_amdgcn_global_load_lds((gp_t)g, (lp_t)l, 16, 0, 0);
}

__device__ __forceinline__ void store_bf16x8(unsigned short* op, float4 a, float4 b) {
  us8 o;
  o[0] = f2bf(a.x); o[1] = f2bf(a.y); o[2] = f2bf(a.z); o[3] = f2bf(a.w);
  o[4] = f2bf(b.x); o[5] = f2bf(b.y); o[6] = f2bf(b.z); o[7] = f2bf(b.w);
  *(us8*)op = o;
}

__device__ __forceinline__ void unpack8(us8 v, float4& a, float4& b) {
  a.x = bf2f(v[0]); a.y = bf2f(v[1]); a.z = bf2f(v[2]); a.w = bf2f(v[3]);
  b.x = bf2f(v[4]); b.y = bf2f(v[5]); b.z = bf2f(v[6]); b.w = bf2f(v[7]);
}

// ---------------- x -> bf16 copy (z: 0=a, 1=b) ----------------
__global__ void cvt_x(const float* __restrict__ xa, const float* __restrict__ xb,
                      unsigned short* __restrict__ oa, unsigned short* __restrict__ ob) {
  int i = blockIdx.x * 256 + threadIdx.x;    // 8-elem chunk; grid.x*256 == NV*DCH/8 exactly
  const float* s = (blockIdx.z == 0) ? xa : xb;
  unsigned short* d = (blockIdx.z == 0) ? oa : ob;
  const float* sp = s + (size_t)i * 8;
  float4 u = *(const float4*)sp;
  float4 v = *(const float4*)(sp + 4);
  store_bf16x8(d + (size_t)i * 8, u, v);
}

// ---------------- weight transpose+cvt, z-batched ----------------
struct WtJob  { const float* w; unsigned short* dst; int ldk, koff; };
struct WtJobs { WtJob j[6]; };

__global__ void wt_kernel(WtJobs jobs) {
  const WtJob J = jobs.j[blockIdx.z];
  int idx = blockIdx.x * 256 + threadIdx.x;
  if (idx >= 512 * 512) return;
  int k = idx >> 9, n = idx & 511;
  J.dst[(size_t)n * J.ldk + J.koff + k] = f2bf(J.w[(size_t)k * 512 + n]);
}

// ---------------- CSR build, z-batched over the 3 edge types ----------------
struct CsrP  { const int* ei; int* counts; int* cursor; int* incl; int* off; int* csrc; int* bsum; int* boff; };
struct Csr3  { CsrP c[3]; };

__global__ void hist_k(Csr3 cs) {
  const CsrP C = cs.c[blockIdx.z];
  int e = blockIdx.x * 256 + threadIdx.x;
  if (e >= NEDGE) return;
  atomicAdd(&C.counts[C.ei[NEDGE + e]], 1);
}

__global__ void scan1(Csr3 cs) {
  const CsrP C = cs.c[blockIdx.z];
  __shared__ int sm[1024];
  int t = threadIdx.x, b = blockIdx.x;
  int i = b * 1024 + t;
  int v = (i < NV) ? C.counts[i] : 0;
  sm[t] = v; __syncthreads();
  for (int off = 1; off < 1024; off <<= 1) {
    int x = sm[t];
    int y = (t >= off) ? sm[t - off] : 0;
    __syncthreads();
    sm[t] = x + y;
    __syncthreads();
  }
  if (i < NV) C.incl[i] = sm[t];
  if (t == 1023) C.bsum[b] = sm[t];
}

__global__ void scan2(Csr3 cs, int nb) {
  const CsrP C = cs.c[blockIdx.z];
  if (threadIdx.x == 0) {
    int run = 0;
    for (int b = 0; b < nb; ++b) { C.boff[b] = run; run += C.bsum[b]; }
  }
}

__global__ void scan3(Csr3 cs) {
  const CsrP C = cs.c[blockIdx.z];
  int i = blockIdx.x * 256 + threadIdx.x;
  if (i < NV) {
    int v = C.incl[i] - C.counts[i] + C.boff[i >> 10];
    C.off[i] = v;
    C.cursor[i] = v;           // live cursor starts at row offset
  }
  if (i == NV) C.off[NV] = NEDGE;
}

__global__ void fill_csr(Csr3 cs) {
  const CsrP C = cs.c[blockIdx.z];
  int e = blockIdx.x * 256 + threadIdx.x;
  if (e >= NEDGE) return;
  int d = C.ei[NEDGE + e];
  int pos = atomicAdd(&C.cursor[d], 1);
  C.csrc[pos] = C.ei[e];
}

// ---------------- merged gather over bf16 sources ----------------
__device__ __forceinline__ void acc_rows16(const unsigned short* __restrict__ xsrc,
                                           const int* __restrict__ csrc,
                                           int s0, int s1, int lane,
                                           float4& a, float4& b) {
  int i = s0;
  for (; i + 1 < s1; i += 2) {
    us8 vA = *(const us8*)(xsrc + (size_t)csrc[i]     * DCH + lane * 8);
    us8 vB = *(const us8*)(xsrc + (size_t)csrc[i + 1] * DCH + lane * 8);
    float4 a0, b0, a1, b1;
    unpack8(vA, a0, b0);
    unpack8(vB, a1, b1);
    a.x += a0.x + a1.x; a.y += a0.y + a1.y; a.z += a0.z + a1.z; a.w += a0.w + a1.w;
    b.x += b0.x + b1.x; b.y += b0.y + b1.y; b.z += b0.z + b1.z; b.w += b0.w + b1.w;
  }
  if (i < s1) {
    us8 v = *(const us8*)(xsrc + (size_t)csrc[i] * DCH + lane * 8);
    float4 a0, b0;
    unpack8(v, a0, b0);
    a.x += a0.x; a.y += a0.y; a.z += a0.z; a.w += a0.w;
    b.x += b0.x; b.y += b0.y; b.z += b0.z; b.w += b0.w;
  }
}

__global__ void gather_all(const unsigned short* __restrict__ xa16,
                           const unsigned short* __restrict__ xb16,
                           const int* __restrict__ off_aa, const int* __restrict__ src_aa,
                           const int* __restrict__ off_ba, const int* __restrict__ src_ba,
                           const int* __restrict__ off_ab, const int* __restrict__ src_ab,
                           unsigned short* __restrict__ hb_aa,
                           unsigned short* __restrict__ hb_ba,
                           unsigned short* __restrict__ hb_ab) {
  int g = blockIdx.x * 256 + threadIdx.x;
  int node = g >> 6, lane = g & 63;
  if (node >= MPAD) return;
  size_t obase = (size_t)node * DCH + lane * 8;
  if (node >= NV) {
    us8 z = {0, 0, 0, 0, 0, 0, 0, 0};
    *(us8*)(hb_aa + obase) = z;
    *(us8*)(hb_ba + obase) = z;
    *(us8*)(hb_ab + obase) = z;
    return;
  }
  float4 da0, da1, db0, db1;
  unpack8(*(const us8*)(xa16 + obase), da0, da1);
  unpack8(*(const us8*)(xb16 + obase), db0, db1);
  float4 aa0 = da0, aa1 = da1;        // h_aa = x_a + sum(x_a srcs)
  float4 ba0 = da0, ba1 = da1;        // h_ba = x_a + sum(x_b srcs)
  float4 ab0 = db0, ab1 = db1;        // h_ab = x_b + sum(x_a srcs)

  acc_rows16(xa16, src_aa, off_aa[node], off_aa[node + 1], lane, aa0, aa1);
  acc_rows16(xb16, src_ba, off_ba[node], off_ba[node + 1], lane, ba0, ba1);
  acc_rows16(xa16, src_ab, off_ab[node], off_ab[node + 1], lane, ab0, ab1);

  store_bf16x8(hb_aa + obase, aa0, aa1);
  store_bf16x8(hb_ba + obase, ba0, ba1);
  store_bf16x8(hb_ab + obase, ab0, ab1);
}

// ---------------- GEMM, z-batched ----------------
// 128x128 tile, BK=64, 4 waves (2x2), 16x16x32 bf16 MFMA.
// MODE 0: out bf16, relu(acc + bias_a[col]), ldc/col_off apply.
// MODE 1: out fp32 = acc + bias_a[col] (+ bias_b[col]), row<NV guard.
struct GemmJob  { const unsigned short* A; int lda; const unsigned short* Bt; int ldb;
                  const float* bias_a; const float* bias_b; void* out; int ldc; int col_off; };
struct GemmJobs { GemmJob j[3]; };

template<int MODE>
__global__ void gemm_tile(GemmJobs jobs) {
  const GemmJob J = jobs.j[blockIdx.z];
  __shared__ __align__(16) unsigned short As[128 * 64];
  __shared__ __align__(16) unsigned short Bs[128 * 64];
  const int t = threadIdx.x;
  const int wave = t >> 6, lane = t & 63;
  const int wr = wave >> 1, wc = wave & 1;
  const int row_base = blockIdx.y * 128;
  const int col_base = blockIdx.x * 128;
  const int rl = lane & 15, kq = lane >> 4;

  f32x4 acc[4][4] = {};

  const int K = J.ldb;
  const int ktiles = K >> 6;
  const unsigned short* Ap = J.A;
  const unsigned short* Bp = J.Bt;
  const int lda = J.lda, ldb = J.ldb;
  for (int kt = 0; kt < ktiles; ++kt) {
    const int k0 = kt << 6;
#pragma unroll
    for (int i = 0; i < 4; ++i) {
      int q = i * 256 + t;
      int r = q >> 3, c = q & 7;
      int cg = c ^ (r & 7);   // pre-swizzled global source -> linear LDS dest
      g2lds16(Ap + (size_t)(row_base + r) * lda + k0 + cg * 8,
              &As[(size_t)(i * 256 + wave * 64) * 8]);
      g2lds16(Bp + (size_t)(col_base + r) * ldb + k0 + cg * 8,
              &Bs[(size_t)(i * 256 + wave * 64) * 8]);
    }
    __syncthreads();
#pragma unroll
    for (int kk = 0; kk < 2; ++kk) {
      bf16x8 af[4], bfr[4];
#pragma unroll
      for (int m = 0; m < 4; ++m) {
        int row = wr * 64 + m * 16 + rl;
        int cc = (kk * 4 + kq) ^ (row & 7);
        af[m] = *(const bf16x8*)&As[(row * 8 + cc) * 8];
      }
#pragma unroll
      for (int n = 0; n < 4; ++n) {
        int col = wc * 64 + n * 16 + rl;
        int cc = (kk * 4 + kq) ^ (col & 7);
        bfr[n] = *(const bf16x8*)&Bs[(col * 8 + cc) * 8];
      }
#pragma unroll
      for (int m = 0; m < 4; ++m)
#pragma unroll
        for (int n = 0; n < 4; ++n)
          acc[m][n] = __builtin_amdgcn_mfma_f32_16x16x32_bf16(af[m], bfr[n], acc[m][n], 0, 0, 0);
    }
    __syncthreads();
  }

  const int orow0 = row_base + wr * 64 + kq * 4;
  const int ocol0 = col_base + wc * 64 + rl;
  if (MODE == 0) {
    unsigned short* out = (unsigned short*)J.out;
#pragma unroll
    for (int m = 0; m < 4; ++m)
#pragma unroll
      for (int n = 0; n < 4; ++n) {
        int col = ocol0 + n * 16;
        float bb = J.bias_a[col];
#pragma unroll
        for (int j = 0; j < 4; ++j) {
          int row = orow0 + m * 16 + j;
          float v = acc[m][n][j] + bb;
          v = fmaxf(v, 0.0f);
          out[(size_t)row * J.ldc + J.col_off + col] = f2bf(v);
        }
      }
  } else {
    float* out = (float*)J.out;
#pragma unroll
    for (int m = 0; m < 4; ++m)
#pragma unroll
      for (int n = 0; n < 4; ++n) {
        int col = ocol0 + n * 16;
        float bb = J.bias_a[col] + (J.bias_b ? J.bias_b[col] : 0.0f);
#pragma unroll
        for (int j = 0; j < 4; ++j) {
          int row = orow0 + m * 16 + j;
          if (row < NV)
            out[(size_t)row * J.ldc + col] = acc[m][n][j] + bb;
        }
      }
  }
}

extern "C" void kernel_launch(void* const* d_in, const int* in_sizes, int n_in,
                              void* d_out, int out_size, void* d_ws, size_t ws_size,
                              hipStream_t stream) {
  const float* x_a  = (const float*)d_in[0];
  const float* x_b  = (const float*)d_in[1];
  const int* ei_aa  = (const int*)d_in[2];
  const int* ei_ab  = (const int*)d_in[3];
  const int* ei_ba  = (const int*)d_in[4];
  const float* w1_aa = (const float*)d_in[5];
  const float* b1_aa = (const float*)d_in[6];
  const float* w2_aa = (const float*)d_in[7];
  const float* b2_aa = (const float*)d_in[8];
  const float* w1_ab = (const float*)d_in[9];
  const float* b1_ab = (const float*)d_in[10];
  const float* w2_ab = (const float*)d_in[11];
  const float* b2_ab = (const float*)d_in[12];
  const float* w1_ba = (const float*)d_in[13];
  const float* b1_ba = (const float*)d_in[14];
  const float* w2_ba = (const float*)d_in[15];
  const float* b2_ba = (const float*)d_in[16];

  char* ws = (char*)d_ws;
  const size_t szH  = (size_t)MPAD * DCH * 2;          // bf16 [MPAD][512]
  const size_t szH2 = (size_t)MPAD * DCH * 2 * 2;      // bf16 [MPAD][1024]
  const size_t szX  = (size_t)NV * DCH * 2;            // bf16 [NV][512]
  size_t o = 0;
  unsigned short* hb_aa = (unsigned short*)(ws + o); o += szH;
  unsigned short* hb_ba = (unsigned short*)(ws + o); o += szH;
  unsigned short* hb_ab = (unsigned short*)(ws + o); o += szH;
  unsigned short* H1c   = (unsigned short*)(ws + o); o += szH2;  // [MPAD][1024]
  unsigned short* H1ab  = (unsigned short*)(ws + o); o += szH;
  unsigned short* xa16  = (unsigned short*)(ws + o); o += szX;
  unsigned short* xb16  = (unsigned short*)(ws + o); o += szX;
  unsigned short* w1t_aa = (unsigned short*)(ws + o); o += 512 * 512 * 2;
  unsigned short* w1t_ba = (unsigned short*)(ws + o); o += 512 * 512 * 2;
  unsigned short* w1t_ab = (unsigned short*)(ws + o); o += 512 * 512 * 2;
  unsigned short* w2tc   = (unsigned short*)(ws + o); o += 512 * 1024 * 2;
  unsigned short* w2t_ab = (unsigned short*)(ws + o); o += 512 * 512 * 2;

  // counts for the 3 types contiguous -> one memset
  int* counts3 = (int*)(ws + o); o += (size_t)3 * NV * 4;

  const int NB1 = (NV + 1023) / 1024;                  // 49
  Csr3 cs;
  const int* eis[3] = { ei_aa, ei_ab, ei_ba };
  for (int tI = 0; tI < 3; ++tI) {
    cs.c[tI].ei     = eis[tI];
    cs.c[tI].counts = counts3 + (size_t)tI * NV;
    cs.c[tI].cursor = (int*)(ws + o); o += (size_t)NV * 4;
    cs.c[tI].incl   = (int*)(ws + o); o += (size_t)NV * 4;
    cs.c[tI].off    = (int*)(ws + o); o += ((size_t)NV + 4) * 4;
    cs.c[tI].csrc   = (int*)(ws + o); o += (size_t)NEDGE * 4;
    cs.c[tI].bsum   = (int*)(ws + o); o += 64 * 4;
    cs.c[tI].boff   = (int*)(ws + o); o += 64 * 4;
  }

  float* out_a = (float*)d_out;
  float* out_b = out_a + (size_t)NV * DCH;

  // weights -> bf16 transposed, one launch (tiny)
  WtJobs wj;
  wj.j[0] = { w1_aa, w1t_aa, 512, 0 };
  wj.j[1] = { w1_ba, w1t_ba, 512, 0 };
  wj.j[2] = { w1_ab, w1t_ab, 512, 0 };
  wj.j[3] = { w2_aa, w2tc, 1024, 0 };
  wj.j[4] = { w2_ba, w2tc, 1024, 512 };
  wj.j[5] = { w2_ab, w2t_ab, 512, 0 };
  wt_kernel<<<dim3(1024, 1, 6), 256, 0, stream>>>(wj);

  // x -> bf16 (working set for gather becomes L3-resident)
  cvt_x<<<dim3(NV * DCH / 8 / 256, 1, 2), 256, 0, stream>>>(x_a, x_b, xa16, xb16);

  // CSR build (5 launches + 1 memset)
  hipMemsetAsync(counts3, 0, (size_t)3 * NV * 4, stream);
  hist_k<<<dim3(587, 1, 3), 256, 0, stream>>>(cs);
  scan1<<<dim3(NB1, 1, 3), 1024, 0, stream>>>(cs);
  scan2<<<dim3(1, 1, 3), 64, 0, stream>>>(cs, NB1);
  scan3<<<dim3(196, 1, 3), 256, 0, stream>>>(cs);
  fill_csr<<<dim3(587, 1, 3), 256, 0, stream>>>(cs);

  // merged gather (aa: a<-a, ba: a<-b, ab: b<-a)
  gather_all<<<MPAD / 4, 256, 0, stream>>>(
      xa16, xb16,
      cs.c[0].off, cs.c[0].csrc,      // aa
      cs.c[2].off, cs.c[2].csrc,      // ba
      cs.c[1].off, cs.c[1].csrc,      // ab
      hb_aa, hb_ba, hb_ab);

  // layer 1: 3 GEMMs in one launch
  GemmJobs g1;
  g1.j[0] = { hb_aa, 512, w1t_aa, 512, b1_aa, nullptr, H1c,  1024, 0 };
  g1.j[1] = { hb_ba, 512, w1t_ba, 512, b1_ba, nullptr, H1c,  1024, 512 };
  g1.j[2] = { hb_ab, 512, w1t_ab, 512, b1_ab, nullptr, H1ab, 512,  0 };
  gemm_tile<0><<<dim3(4, MPAD / 128, 3), 256, 0, stream>>>(g1);

  // layer 2: merged-K GEMM (aa+ba) and ab GEMM in one launch
  GemmJobs g2;
  g2.j[0] = { H1c,  1024, w2tc,   1024, b2_aa, b2_ba,  out_a, 512, 0 };
  g2.j[1] = { H1ab, 512,  w2t_ab, 512,  b2_ab, nullptr, out_b, 512, 0 };
  g2.j[2] = g2.j[1];   // unused (grid z=2)
  gemm_tile<1><<<dim3(4, MPAD / 128, 2), 256, 0, stream>>>(g2);
}

// Round 5
// 485.137 us; speedup vs baseline: 13.4877x; 1.0185x over previous
//
#include <hip/hip_runtime.h>

#define NV    50000
#define DCH   512
#define NEDGE 150000
#define MPAD  50048   // 391 * 128

typedef float  f32x4  __attribute__((ext_vector_type(4)));
typedef __bf16 bf16x8 __attribute__((ext_vector_type(8)));
typedef unsigned short us8 __attribute__((ext_vector_type(8)));

__device__ __forceinline__ unsigned short f2bf(float f) {
  unsigned int u = __builtin_bit_cast(unsigned int, f);
  u += 0x7fffu + ((u >> 16) & 1u);
  return (unsigned short)(u >> 16);
}

__device__ __forceinline__ float bf2f(unsigned short h) {
  return __builtin_bit_cast(float, (unsigned int)h << 16);
}

__device__ __forceinline__ void g2lds16(const void* g, void* l) {
  typedef const __attribute__((address_space(1))) unsigned int* gp_t;
  typedef __attribute__((address_space(3))) unsigned int* lp_t;
  __builtin_amdgcn_global_load_lds((gp_t)g, (lp_t)l, 16, 0, 0);
}

__device__ __forceinline__ void store_bf16x8(unsigned short* op, float4 a, float4 b) {
  us8 o;
  o[0] = f2bf(a.x); o[1] = f2bf(a.y); o[2] = f2bf(a.z); o[3] = f2bf(a.w);
  o[4] = f2bf(b.x); o[5] = f2bf(b.y); o[6] = f2bf(b.z); o[7] = f2bf(b.w);
  *(us8*)op = o;
}

__device__ __forceinline__ void unpack8(us8 v, float4& a, float4& b) {
  a.x = bf2f(v[0]); a.y = bf2f(v[1]); a.z = bf2f(v[2]); a.w = bf2f(v[3]);
  b.x = bf2f(v[4]); b.y = bf2f(v[5]); b.z = bf2f(v[6]); b.w = bf2f(v[7]);
}

// ---------------- x -> bf16 copy (z: 0=a, 1=b) ----------------
__global__ void cvt_x(const float* __restrict__ xa, const float* __restrict__ xb,
                      unsigned short* __restrict__ oa, unsigned short* __restrict__ ob) {
  int i = blockIdx.x * 256 + threadIdx.x;    // 8-elem chunk; grid.x*256 == NV*DCH/8 exactly
  const float* s = (blockIdx.z == 0) ? xa : xb;
  unsigned short* d = (blockIdx.z == 0) ? oa : ob;
  const float* sp = s + (size_t)i * 8;
  float4 u = *(const float4*)sp;
  float4 v = *(const float4*)(sp + 4);
  store_bf16x8(d + (size_t)i * 8, u, v);
}

// ---------------- weight transpose+cvt, z-batched ----------------
struct WtJob  { const float* w; unsigned short* dst; int ldk, koff; };
struct WtJobs { WtJob j[6]; };

__global__ void wt_kernel(WtJobs jobs) {
  const WtJob J = jobs.j[blockIdx.z];
  int idx = blockIdx.x * 256 + threadIdx.x;
  if (idx >= 512 * 512) return;
  int k = idx >> 9, n = idx & 511;
  J.dst[(size_t)n * J.ldk + J.koff + k] = f2bf(J.w[(size_t)k * 512 + n]);
}

// ---------------- CSR build, z-batched over the 3 edge types ----------------
struct CsrP  { const int* ei; int* counts; int* cursor; int* incl; int* off; int* csrc; int* bsum; int* boff; };
struct Csr3  { CsrP c[3]; };

__global__ void hist_k(Csr3 cs) {
  const CsrP C = cs.c[blockIdx.z];
  int e = blockIdx.x * 256 + threadIdx.x;
  if (e >= NEDGE) return;
  atomicAdd(&C.counts[C.ei[NEDGE + e]], 1);
}

__global__ void scan1(Csr3 cs) {
  const CsrP C = cs.c[blockIdx.z];
  __shared__ int sm[1024];
  int t = threadIdx.x, b = blockIdx.x;
  int i = b * 1024 + t;
  int v = (i < NV) ? C.counts[i] : 0;
  sm[t] = v; __syncthreads();
  for (int off = 1; off < 1024; off <<= 1) {
    int x = sm[t];
    int y = (t >= off) ? sm[t - off] : 0;
    __syncthreads();
    sm[t] = x + y;
    __syncthreads();
  }
  if (i < NV) C.incl[i] = sm[t];
  if (t == 1023) C.bsum[b] = sm[t];
}

__global__ void scan2(Csr3 cs, int nb) {
  const CsrP C = cs.c[blockIdx.z];
  if (threadIdx.x == 0) {
    int run = 0;
    for (int b = 0; b < nb; ++b) { C.boff[b] = run; run += C.bsum[b]; }
  }
}

__global__ void scan3(Csr3 cs) {
  const CsrP C = cs.c[blockIdx.z];
  int i = blockIdx.x * 256 + threadIdx.x;
  if (i < NV) {
    int v = C.incl[i] - C.counts[i] + C.boff[i >> 10];
    C.off[i] = v;
    C.cursor[i] = v;           // live cursor starts at row offset
  }
  if (i == NV) C.off[NV] = NEDGE;
}

__global__ void fill_csr(Csr3 cs) {
  const CsrP C = cs.c[blockIdx.z];
  int e = blockIdx.x * 256 + threadIdx.x;
  if (e >= NEDGE) return;
  int d = C.ei[NEDGE + e];
  int pos = atomicAdd(&C.cursor[d], 1);
  C.csrc[pos] = C.ei[e];
}

// ---------------- merged gather over bf16 sources ----------------
__device__ __forceinline__ void acc_rows16(const unsigned short* __restrict__ xsrc,
                                           const int* __restrict__ csrc,
                                           int s0, int s1, int lane,
                                           float4& a, float4& b) {
  int i = s0;
  for (; i + 1 < s1; i += 2) {
    us8 vA = *(const us8*)(xsrc + (size_t)csrc[i]     * DCH + lane * 8);
    us8 vB = *(const us8*)(xsrc + (size_t)csrc[i + 1] * DCH + lane * 8);
    float4 a0, b0, a1, b1;
    unpack8(vA, a0, b0);
    unpack8(vB, a1, b1);
    a.x += a0.x + a1.x; a.y += a0.y + a1.y; a.z += a0.z + a1.z; a.w += a0.w + a1.w;
    b.x += b0.x + b1.x; b.y += b0.y + b1.y; b.z += b0.z + b1.z; b.w += b0.w + b1.w;
  }
  if (i < s1) {
    us8 v = *(const us8*)(xsrc + (size_t)csrc[i] * DCH + lane * 8);
    float4 a0, b0;
    unpack8(v, a0, b0);
    a.x += a0.x; a.y += a0.y; a.z += a0.z; a.w += a0.w;
    b.x += b0.x; b.y += b0.y; b.z += b0.z; b.w += b0.w;
  }
}

__global__ void gather_all(const unsigned short* __restrict__ xa16,
                           const unsigned short* __restrict__ xb16,
                           const int* __restrict__ off_aa, const int* __restrict__ src_aa,
                           const int* __restrict__ off_ba, const int* __restrict__ src_ba,
                           const int* __restrict__ off_ab, const int* __restrict__ src_ab,
                           unsigned short* __restrict__ hb_aa,
                           unsigned short* __restrict__ hb_ba,
                           unsigned short* __restrict__ hb_ab) {
  int g = blockIdx.x * 256 + threadIdx.x;
  int node = g >> 6, lane = g & 63;
  if (node >= MPAD) return;
  size_t obase = (size_t)node * DCH + lane * 8;
  if (node >= NV) {
    us8 z = {0, 0, 0, 0, 0, 0, 0, 0};
    *(us8*)(hb_aa + obase) = z;
    *(us8*)(hb_ba + obase) = z;
    *(us8*)(hb_ab + obase) = z;
    return;
  }
  float4 da0, da1, db0, db1;
  unpack8(*(const us8*)(xa16 + obase), da0, da1);
  unpack8(*(const us8*)(xb16 + obase), db0, db1);
  float4 aa0 = da0, aa1 = da1;        // h_aa = x_a + sum(x_a srcs)
  float4 ba0 = da0, ba1 = da1;        // h_ba = x_a + sum(x_b srcs)
  float4 ab0 = db0, ab1 = db1;        // h_ab = x_b + sum(x_a srcs)

  acc_rows16(xa16, src_aa, off_aa[node], off_aa[node + 1], lane, aa0, aa1);
  acc_rows16(xb16, src_ba, off_ba[node], off_ba[node + 1], lane, ba0, ba1);
  acc_rows16(xa16, src_ab, off_ab[node], off_ab[node + 1], lane, ab0, ab1);

  store_bf16x8(hb_aa + obase, aa0, aa1);
  store_bf16x8(hb_ba + obase, ba0, ba1);
  store_bf16x8(hb_ab + obase, ab0, ab1);
}

// ---------------- GEMM, z-batched, XCD-chunk-swizzled ----------------
// 128x128 tile, BK=64, 4 waves (2x2), 16x16x32 bf16 MFMA.
// Grid MUST be (4, 391, z): NWG=1564 per slice; bijective chunked swizzle
// (m204) gives each XCD a contiguous wgid range -> the 4 col-tiles of an
// A-row-panel run on ONE XCD -> A fetched once into that L2.
// MODE 0: out bf16, relu(acc + bias_a[col]), ldc/col_off apply.
// MODE 1: out fp32 = acc + bias_a[col] (+ bias_b[col]), row<NV guard.
struct GemmJob  { const unsigned short* A; int lda; const unsigned short* Bt; int ldb;
                  const float* bias_a; const float* bias_b; void* out; int ldc; int col_off; };
struct GemmJobs { GemmJob j[3]; };

template<int MODE>
__global__ void gemm_tile(GemmJobs jobs) {
  const GemmJob J = jobs.j[blockIdx.z];
  __shared__ __align__(16) unsigned short As[128 * 64];
  __shared__ __align__(16) unsigned short Bs[128 * 64];
  const int t = threadIdx.x;
  const int wave = t >> 6, lane = t & 63;
  const int wr = wave >> 1, wc = wave & 1;

  // ---- T1 bijective XCD-chunked swizzle (nwg=1564, q=195, r=4) ----
  // Each flat%8 class is XCD-pure for any constant per-slice offset, so the
  // chunk->XCD labels may rotate with z but chunks never split across XCDs.
  const int flat = blockIdx.x + (blockIdx.y << 2);
  const int xcd = flat & 7, idx = flat >> 3;
  const int wgid = (xcd < 4 ? xcd * 196 : 784 + (xcd - 4) * 195) + idx;
  const int row_base = (wgid >> 2) * 128;
  const int col_base = (wgid & 3) * 128;

  const int rl = lane & 15, kq = lane >> 4;

  f32x4 acc[4][4] = {};

  const int K = J.ldb;
  const int ktiles = K >> 6;
  const unsigned short* Ap = J.A;
  const unsigned short* Bp = J.Bt;
  const int lda = J.lda, ldb = J.ldb;
  for (int kt = 0; kt < ktiles; ++kt) {
    const int k0 = kt << 6;
#pragma unroll
    for (int i = 0; i < 4; ++i) {
      int q = i * 256 + t;
      int r = q >> 3, c = q & 7;
      int cg = c ^ (r & 7);   // pre-swizzled global source -> linear LDS dest
      g2lds16(Ap + (size_t)(row_base + r) * lda + k0 + cg * 8,
              &As[(size_t)(i * 256 + wave * 64) * 8]);
      g2lds16(Bp + (size_t)(col_base + r) * ldb + k0 + cg * 8,
              &Bs[(size_t)(i * 256 + wave * 64) * 8]);
    }
    __syncthreads();
#pragma unroll
    for (int kk = 0; kk < 2; ++kk) {
      bf16x8 af[4], bfr[4];
#pragma unroll
      for (int m = 0; m < 4; ++m) {
        int row = wr * 64 + m * 16 + rl;
        int cc = (kk * 4 + kq) ^ (row & 7);
        af[m] = *(const bf16x8*)&As[(row * 8 + cc) * 8];
      }
#pragma unroll
      for (int n = 0; n < 4; ++n) {
        int col = wc * 64 + n * 16 + rl;
        int cc = (kk * 4 + kq) ^ (col & 7);
        bfr[n] = *(const bf16x8*)&Bs[(col * 8 + cc) * 8];
      }
#pragma unroll
      for (int m = 0; m < 4; ++m)
#pragma unroll
        for (int n = 0; n < 4; ++n)
          acc[m][n] = __builtin_amdgcn_mfma_f32_16x16x32_bf16(af[m], bfr[n], acc[m][n], 0, 0, 0);
    }
    __syncthreads();
  }

  const int orow0 = row_base + wr * 64 + kq * 4;
  const int ocol0 = col_base + wc * 64 + rl;
  if (MODE == 0) {
    unsigned short* out = (unsigned short*)J.out;
#pragma unroll
    for (int m = 0; m < 4; ++m)
#pragma unroll
      for (int n = 0; n < 4; ++n) {
        int col = ocol0 + n * 16;
        float bb = J.bias_a[col];
#pragma unroll
        for (int j = 0; j < 4; ++j) {
          int row = orow0 + m * 16 + j;
          float v = acc[m][n][j] + bb;
          v = fmaxf(v, 0.0f);
          out[(size_t)row * J.ldc + J.col_off + col] = f2bf(v);
        }
      }
  } else {
    float* out = (float*)J.out;
#pragma unroll
    for (int m = 0; m < 4; ++m)
#pragma unroll
      for (int n = 0; n < 4; ++n) {
        int col = ocol0 + n * 16;
        float bb = J.bias_a[col] + (J.bias_b ? J.bias_b[col] : 0.0f);
#pragma unroll
        for (int j = 0; j < 4; ++j) {
          int row = orow0 + m * 16 + j;
          if (row < NV)
            out[(size_t)row * J.ldc + col] = acc[m][n][j] + bb;
        }
      }
  }
}

extern "C" void kernel_launch(void* const* d_in, const int* in_sizes, int n_in,
                              void* d_out, int out_size, void* d_ws, size_t ws_size,
                              hipStream_t stream) {
  const float* x_a  = (const float*)d_in[0];
  const float* x_b  = (const float*)d_in[1];
  const int* ei_aa  = (const int*)d_in[2];
  const int* ei_ab  = (const int*)d_in[3];
  const int* ei_ba  = (const int*)d_in[4];
  const float* w1_aa = (const float*)d_in[5];
  const float* b1_aa = (const float*)d_in[6];
  const float* w2_aa = (const float*)d_in[7];
  const float* b2_aa = (const float*)d_in[8];
  const float* w1_ab = (const float*)d_in[9];
  const float* b1_ab = (const float*)d_in[10];
  const float* w2_ab = (const float*)d_in[11];
  const float* b2_ab = (const float*)d_in[12];
  const float* w1_ba = (const float*)d_in[13];
  const float* b1_ba = (const float*)d_in[14];
  const float* w2_ba = (const float*)d_in[15];
  const float* b2_ba = (const float*)d_in[16];

  char* ws = (char*)d_ws;
  const size_t szH  = (size_t)MPAD * DCH * 2;          // bf16 [MPAD][512]
  const size_t szH2 = (size_t)MPAD * DCH * 2 * 2;      // bf16 [MPAD][1024]
  const size_t szX  = (size_t)NV * DCH * 2;            // bf16 [NV][512]
  size_t o = 0;
  unsigned short* hb_aa = (unsigned short*)(ws + o); o += szH;
  unsigned short* hb_ba = (unsigned short*)(ws + o); o += szH;
  unsigned short* hb_ab = (unsigned short*)(ws + o); o += szH;
  unsigned short* H1c   = (unsigned short*)(ws + o); o += szH2;  // [MPAD][1024]
  unsigned short* H1ab  = (unsigned short*)(ws + o); o += szH;
  unsigned short* xa16  = (unsigned short*)(ws + o); o += szX;
  unsigned short* xb16  = (unsigned short*)(ws + o); o += szX;
  unsigned short* w1t_aa = (unsigned short*)(ws + o); o += 512 * 512 * 2;
  unsigned short* w1t_ba = (unsigned short*)(ws + o); o += 512 * 512 * 2;
  unsigned short* w1t_ab = (unsigned short*)(ws + o); o += 512 * 512 * 2;
  unsigned short* w2tc   = (unsigned short*)(ws + o); o += 512 * 1024 * 2;
  unsigned short* w2t_ab = (unsigned short*)(ws + o); o += 512 * 512 * 2;

  // counts for the 3 types contiguous -> one memset
  int* counts3 = (int*)(ws + o); o += (size_t)3 * NV * 4;

  const int NB1 = (NV + 1023) / 1024;                  // 49
  Csr3 cs;
  const int* eis[3] = { ei_aa, ei_ab, ei_ba };
  for (int tI = 0; tI < 3; ++tI) {
    cs.c[tI].ei     = eis[tI];
    cs.c[tI].counts = counts3 + (size_t)tI * NV;
    cs.c[tI].cursor = (int*)(ws + o); o += (size_t)NV * 4;
    cs.c[tI].incl   = (int*)(ws + o); o += (size_t)NV * 4;
    cs.c[tI].off    = (int*)(ws + o); o += ((size_t)NV + 4) * 4;
    cs.c[tI].csrc   = (int*)(ws + o); o += (size_t)NEDGE * 4;
    cs.c[tI].bsum   = (int*)(ws + o); o += 64 * 4;
    cs.c[tI].boff   = (int*)(ws + o); o += 64 * 4;
  }

  float* out_a = (float*)d_out;
  float* out_b = out_a + (size_t)NV * DCH;

  // weights -> bf16 transposed, one launch (tiny)
  WtJobs wj;
  wj.j[0] = { w1_aa, w1t_aa, 512, 0 };
  wj.j[1] = { w1_ba, w1t_ba, 512, 0 };
  wj.j[2] = { w1_ab, w1t_ab, 512, 0 };
  wj.j[3] = { w2_aa, w2tc, 1024, 0 };
  wj.j[4] = { w2_ba, w2tc, 1024, 512 };
  wj.j[5] = { w2_ab, w2t_ab, 512, 0 };
  wt_kernel<<<dim3(1024, 1, 6), 256, 0, stream>>>(wj);

  // x -> bf16 (working set for gather becomes L3-resident)
  cvt_x<<<dim3(NV * DCH / 8 / 256, 1, 2), 256, 0, stream>>>(x_a, x_b, xa16, xb16);

  // CSR build (5 launches + 1 memset)
  hipMemsetAsync(counts3, 0, (size_t)3 * NV * 4, stream);
  hist_k<<<dim3(587, 1, 3), 256, 0, stream>>>(cs);
  scan1<<<dim3(NB1, 1, 3), 1024, 0, stream>>>(cs);
  scan2<<<dim3(1, 1, 3), 64, 0, stream>>>(cs, NB1);
  scan3<<<dim3(196, 1, 3), 256, 0, stream>>>(cs);
  fill_csr<<<dim3(587, 1, 3), 256, 0, stream>>>(cs);

  // merged gather (aa: a<-a, ba: a<-b, ab: b<-a)
  gather_all<<<MPAD / 4, 256, 0, stream>>>(
      xa16, xb16,
      cs.c[0].off, cs.c[0].csrc,      // aa
      cs.c[2].off, cs.c[2].csrc,      // ba
      cs.c[1].off, cs.c[1].csrc,      // ab
      hb_aa, hb_ba, hb_ab);

  // layer 1: 3 GEMMs in one launch
  GemmJobs g1;
  g1.j[0] = { hb_aa, 512, w1t_aa, 512, b1_aa, nullptr, H1c,  1024, 0 };
  g1.j[1] = { hb_ba, 512, w1t_ba, 512, b1_ba, nullptr, H1c,  1024, 512 };
  g1.j[2] = { hb_ab, 512, w1t_ab, 512, b1_ab, nullptr, H1ab, 512,  0 };
  gemm_tile<0><<<dim3(4, MPAD / 128, 3), 256, 0, stream>>>(g1);

  // layer 2: merged-K GEMM (aa+ba) and ab GEMM in one launch
  GemmJobs g2;
  g2.j[0] = { H1c,  1024, w2tc,   1024, b2_aa, b2_ba,  out_a, 512, 0 };
  g2.j[1] = { H1ab, 512,  w2t_ab, 512,  b2_ab, nullptr, out_b, 512, 0 };
  g2.j[2] = g2.j[1];   // unused (grid z=2)
  gemm_tile<1><<<dim3(4, MPAD / 128, 2), 256, 0, stream>>>(g2);
}